// Round 7
// baseline (195.535 us; speedup 1.0000x reference)
//
#include <hip/hip_runtime.h>
#include <cstddef>

typedef unsigned short u16;
typedef __attribute__((ext_vector_type(4))) float floatx4;
typedef __attribute__((ext_vector_type(8))) short short8;

#define TT 2048
#define DD 1024
#define NH 16
#define ATT_SCALE (1.0f / 32.0f)
#define PSTR 72  // padded LDS row stride (u16)

__device__ __forceinline__ u16 f2bf(float f) {
  unsigned u = __builtin_bit_cast(unsigned, f);
  u += 0x7fffu + ((u >> 16) & 1u);  // RNE
  return (u16)(u >> 16);
}

// pack two f32 -> (bf16,bf16) in one u32, a in low half (RNE)
__device__ __forceinline__ unsigned pack2(float a, float b) {
#if __has_builtin(__builtin_amdgcn_cvt_pk_bf16_f32)
  auto t = __builtin_amdgcn_cvt_pk_bf16_f32(a, b);
  return __builtin_bit_cast(unsigned, t);
#else
  unsigned ua = __builtin_bit_cast(unsigned, a);
  ua += 0x7fffu + ((ua >> 16) & 1u);
  unsigned ub = __builtin_bit_cast(unsigned, b);
  ub += 0x7fffu + ((ub >> 16) & 1u);
  return (ua >> 16) | (ub & 0xffff0000u);
#endif
}

// async global->LDS, 16B per lane (LDS dest wave-uniform base + lane*16)
__device__ __forceinline__ void g2l16(const u16* g, u16* l) {
#if __has_builtin(__builtin_amdgcn_global_load_lds)
  __builtin_amdgcn_global_load_lds(
      (const __attribute__((address_space(1))) unsigned int*)g,
      (__attribute__((address_space(3))) unsigned int*)l, 16, 0, 0);
#else
  *(int4*)l = *(const int4*)g;
#endif
}

// scale bf16x8 by 1/32 (exact: exponent shift)
__device__ __forceinline__ short8 scale_q(short8 q) {
  short8 r;
#pragma unroll
  for (int i = 0; i < 8; ++i) {
    float f = __builtin_bit_cast(float, ((unsigned)(u16)q[i]) << 16) * ATT_SCALE;
    r[i] = (short)f2bf(f);
  }
  return r;
}

// one kernel for all three fp32->bf16 conversions (outputs contiguous in ws)
__global__ __launch_bounds__(256) void cvt3_kernel(const float* __restrict__ a,
                                                   const float* __restrict__ b,
                                                   const float* __restrict__ c,
                                                   u16* __restrict__ out,
                                                   int na, int nb, int nc) {
  int i = blockIdx.x * 256 + threadIdx.x;
  const float* src;
  int j;
  if (i < na) { src = a; j = i; }
  else if (i < na + nb) { src = b; j = i - na; }
  else if (i < na + nb + nc) { src = c; j = i - na - nb; }
  else return;
  float4 v = ((const float4*)src)[j];
  ((ushort4*)out)[i] = make_ushort4(f2bf(v.x), f2bf(v.y), f2bf(v.z), f2bf(v.w));
}

// C[m,n] = sum_k A[m,k]*Bm[n,k]. 128xBN tile, BK=32, global_load_lds staging.
// MODE 0: fp32 out (width N). MODE 1: bf16 out (width N).
// MODE 2 (qkv-fused): cols<2048 -> bf16 qk buffer (width 2048);
//                     cols>=2048 -> V written TRANSPOSED to vt[(b*1024+e-2048)*2048+t].
template <int MODE, int BN>
__global__ __launch_bounds__(256) void gemm_bt(const u16* __restrict__ A,
                                               const u16* __restrict__ Bm,
                                               void* __restrict__ C,
                                               u16* __restrict__ vt,
                                               int M, int N, int K) {
  constexpr int NT = BN / 32;
  __shared__ u16 As[128 * 32];
  __shared__ u16 Bs[BN * 32];
  const int tid = threadIdx.x;
  const int lane = tid & 63;
  const int wave = tid >> 6;
  const int quad = lane >> 4;
  const int l16 = lane & 15;
  const int wm = (wave >> 1) * 64;
  const int wn = (wave & 1) * (BN / 2);
  const int m0 = blockIdx.x * 128;
  const int n0 = blockIdx.y * BN;

  const int srow = wave * 16 + (lane >> 2);
  const int scol = (lane & 3) * 8;
  const int sl = wave * 512 + lane * 8;

  floatx4 acc[4][NT] = {};

  for (int k0 = 0; k0 < K; k0 += 32) {
    __syncthreads();
    g2l16(&A[(size_t)(m0 + srow) * K + k0 + scol], &As[sl]);
    g2l16(&A[(size_t)(m0 + 64 + srow) * K + k0 + scol], &As[2048 + sl]);
    g2l16(&Bm[(size_t)(n0 + srow) * K + k0 + scol], &Bs[sl]);
    if (BN == 128)
      g2l16(&Bm[(size_t)(n0 + 64 + srow) * K + k0 + scol], &Bs[2048 + sl]);
    __syncthreads();

    short8 af[4];
#pragma unroll
    for (int mt = 0; mt < 4; ++mt)
      af[mt] = *(const short8*)&As[(wm + mt * 16 + l16) * 32 + quad * 8];
#pragma unroll
    for (int nt = 0; nt < NT; ++nt) {
      short8 bf = *(const short8*)&Bs[(wn + nt * 16 + l16) * 32 + quad * 8];
#pragma unroll
      for (int mt = 0; mt < 4; ++mt)
        acc[mt][nt] = __builtin_amdgcn_mfma_f32_16x16x32_bf16(af[mt], bf, acc[mt][nt], 0, 0, 0);
    }
  }

  if (MODE == 2 && n0 >= 2048) {
    // V region: transposed store. whole 128-row tile shares one batch (2048%128==0)
    const int bidx = m0 >> 11;
    const int tbase = (m0 & 2047) + wm;
#pragma unroll
    for (int mt = 0; mt < 4; ++mt)
#pragma unroll
      for (int nt = 0; nt < NT; ++nt) {
        int gn = n0 + wn + nt * 16 + l16;
        size_t vrow = (size_t)(bidx * 1024 + gn - 2048);
        int t = tbase + mt * 16 + quad * 4;
        uint2 val;
        val.x = pack2(acc[mt][nt][0], acc[mt][nt][1]);
        val.y = pack2(acc[mt][nt][2], acc[mt][nt][3]);
        *(uint2*)&vt[vrow * TT + t] = val;
      }
  } else {
    const int cw = (MODE == 2) ? 2048 : N;
#pragma unroll
    for (int mt = 0; mt < 4; ++mt)
#pragma unroll
      for (int nt = 0; nt < NT; ++nt)
#pragma unroll
        for (int r = 0; r < 4; ++r) {
          int gm = m0 + wm + mt * 16 + quad * 4 + r;
          int gn = n0 + wn + nt * 16 + l16;
          float v = acc[mt][nt][r];
          if (MODE >= 1)
            ((u16*)C)[(size_t)gm * cw + gn] = f2bf(v);
          else
            ((float*)C)[(size_t)gm * cw + gn] = v;
        }
  }
}

// Paired flash attention, operand-swapped S^T so each lane owns one query row
// with 4-contiguous key groups: P spills as packed ds_write_b64, psum is a
// per-lane scalar. Single-buffered K/V staging -> 36.9 KB LDS -> 4 blocks/CU.
__global__ __launch_bounds__(256) void attn_flash4(const u16* __restrict__ qk,
                                                   const u16* __restrict__ vt,
                                                   u16* __restrict__ z) {
  __shared__ u16 Ks[64 * PSTR];        // Ks[key][d]
  __shared__ u16 Vs[64 * PSTR];        // Vs[d][key]
  __shared__ u16 Ps[4][2][16 * PSTR];  // per-wave, per-tile: Ps[w][tile][query][key]

  const int tid = threadIdx.x;
  const int lane = tid & 63;
  const int wave = tid >> 6;
  const int quad = lane >> 4;
  const int l16 = lane & 15;

  const int p = blockIdx.x;  // 0..15
  const int qtA = p, qtB = 31 - p;
  const int bh = blockIdx.y;
  const int b = bh >> 4, h = bh & 15;

  const size_t bbase = (size_t)b * TT * 2048;
  const u16* qg = qk + bbase + h * 64;
  const u16* kg = qk + bbase + 1024 + h * 64;
  const u16* vtg = vt + (size_t)bh * 64 * TT;

  short8 qfA[2], qfB[2];
  {
    const size_t ra = (size_t)(qtA * 64 + wave * 16 + l16) * 2048;
    const size_t rb = (size_t)(qtB * 64 + wave * 16 + l16) * 2048;
    qfA[0] = scale_q(*(const short8*)&qg[ra + quad * 8]);
    qfA[1] = scale_q(*(const short8*)&qg[ra + 32 + quad * 8]);
    qfB[0] = scale_q(*(const short8*)&qg[rb + quad * 8]);
    qfB[1] = scale_q(*(const short8*)&qg[rb + 32 + quad * 8]);
  }

  floatx4 OA[4] = {}, OB[4] = {};
  float psA = 0.f, psB = 0.f;  // per-lane partial row-sum for query l16

  const int str = tid >> 2, sc = (tid & 3) * 16;
  const int nktA = qtA + 1, nktB = qtB + 1;
  const int wl = wave * 16 + l16;  // within-tile query index (mask threshold)

  for (int kt = 0; kt < nktB; ++kt) {
    const int kt0 = kt * 64;
    __syncthreads();
    *(int4*)&Ks[str * PSTR + sc] = *(const int4*)&kg[(size_t)(kt0 + str) * 2048 + sc];
    *(int4*)&Ks[str * PSTR + sc + 8] = *(const int4*)&kg[(size_t)(kt0 + str) * 2048 + sc + 8];
    *(int4*)&Vs[str * PSTR + sc] = *(const int4*)&vtg[(size_t)str * TT + kt0 + sc];
    *(int4*)&Vs[str * PSTR + sc + 8] = *(const int4*)&vtg[(size_t)str * TT + kt0 + sc + 8];
    __syncthreads();

    const bool actA = (kt < nktA);
    const bool diagA = (kt == qtA), diagB = (kt == qtB);

    // S^T = K·Q^T: lane(quad,l16) gets S[query=l16][key = nt*16 + quad*4 + r]
    floatx4 sB[4], sA[4];
#pragma unroll
    for (int nt = 0; nt < 4; ++nt) {
      short8 k0 = *(const short8*)&Ks[(nt * 16 + l16) * PSTR + quad * 8];
      short8 k1 = *(const short8*)&Ks[(nt * 16 + l16) * PSTR + 32 + quad * 8];
      floatx4 zz = {0.f, 0.f, 0.f, 0.f};
      sB[nt] = __builtin_amdgcn_mfma_f32_16x16x32_bf16(k0, qfB[0], zz, 0, 0, 0);
      sB[nt] = __builtin_amdgcn_mfma_f32_16x16x32_bf16(k1, qfB[1], sB[nt], 0, 0, 0);
      if (actA) {
        sA[nt] = __builtin_amdgcn_mfma_f32_16x16x32_bf16(k0, qfA[0], zz, 0, 0, 0);
        sA[nt] = __builtin_amdgcn_mfma_f32_16x16x32_bf16(k1, qfA[1], sA[nt], 0, 0, 0);
      }
    }

    // exp (Q pre-scaled, |s|<=32 so no overflow), scalar psum, packed b64 P spill
#pragma unroll
    for (int nt = 0; nt < 4; ++nt) {
      float e[4];
#pragma unroll
      for (int r = 0; r < 4; ++r) {
        int kl = nt * 16 + quad * 4 + r;
        e[r] = (!diagB || kl <= wl) ? __expf(sB[nt][r]) : 0.f;
        psB += e[r];
      }
      uint2 val = {pack2(e[0], e[1]), pack2(e[2], e[3])};
      *(uint2*)&Ps[wave][1][l16 * PSTR + nt * 16 + quad * 4] = val;
    }
    if (actA) {
#pragma unroll
      for (int nt = 0; nt < 4; ++nt) {
        float e[4];
#pragma unroll
        for (int r = 0; r < 4; ++r) {
          int kl = nt * 16 + quad * 4 + r;
          e[r] = (!diagA || kl <= wl) ? __expf(sA[nt][r]) : 0.f;
          psA += e[r];
        }
        uint2 val = {pack2(e[0], e[1]), pack2(e[2], e[3])};
        *(uint2*)&Ps[wave][0][l16 * PSTR + nt * 16 + quad * 4] = val;
      }
    }

    // PV: A-frags straight from Ps (same-wave DS ordering), B-frags from Vs
    short8 pB0 = *(const short8*)&Ps[wave][1][l16 * PSTR + quad * 8];
    short8 pB1 = *(const short8*)&Ps[wave][1][l16 * PSTR + 32 + quad * 8];
    short8 pA0, pA1;
    if (actA) {
      pA0 = *(const short8*)&Ps[wave][0][l16 * PSTR + quad * 8];
      pA1 = *(const short8*)&Ps[wave][0][l16 * PSTR + 32 + quad * 8];
    }
#pragma unroll
    for (int nt = 0; nt < 4; ++nt) {
      short8 v0 = *(const short8*)&Vs[(nt * 16 + l16) * PSTR + quad * 8];
      short8 v1 = *(const short8*)&Vs[(nt * 16 + l16) * PSTR + 32 + quad * 8];
      OB[nt] = __builtin_amdgcn_mfma_f32_16x16x32_bf16(pB0, v0, OB[nt], 0, 0, 0);
      OB[nt] = __builtin_amdgcn_mfma_f32_16x16x32_bf16(pB1, v1, OB[nt], 0, 0, 0);
      if (actA) {
        OA[nt] = __builtin_amdgcn_mfma_f32_16x16x32_bf16(pA0, v0, OA[nt], 0, 0, 0);
        OA[nt] = __builtin_amdgcn_mfma_f32_16x16x32_bf16(pA1, v1, OA[nt], 0, 0, 0);
      }
    }
  }

  // total row-sums: reduce the quad-partials (queries live at l16)
  psA += __shfl_xor(psA, 16, 64);
  psA += __shfl_xor(psA, 32, 64);
  psB += __shfl_xor(psB, 16, 64);
  psB += __shfl_xor(psB, 32, 64);

  // O rows are query=quad*4+r (C-layout); fetch that query's sum via bpermute
#pragma unroll
  for (int r = 0; r < 4; ++r) {
    float rlA = 1.0f / __shfl(psA, quad * 4 + r, 64);
    float rlB = 1.0f / __shfl(psB, quad * 4 + r, 64);
    int qa = qtA * 64 + wave * 16 + quad * 4 + r;
    int qb = qtB * 64 + wave * 16 + quad * 4 + r;
#pragma unroll
    for (int nt = 0; nt < 4; ++nt) {
      int d = nt * 16 + l16;
      z[(size_t)(b * TT + qa) * DD + h * 64 + d] = f2bf(OA[nt][r] * rlA);
      z[(size_t)(b * TT + qb) * DD + h * 64 + d] = f2bf(OB[nt][r] * rlB);
    }
  }
}

extern "C" void kernel_launch(void* const* d_in, const int* in_sizes, int n_in,
                              void* d_out, int out_size, void* d_ws, size_t ws_size,
                              hipStream_t stream) {
  const float* x  = (const float*)d_in[0];   // [2,2048,1024]
  const float* Wa = (const float*)d_in[1];   // [3072,1024]
  const float* Wo = (const float*)d_in[2];   // [1024,1024]
  float* out = (float*)d_out;                // [2,2048,1024] fp32

  // 48 MB workspace, no overlays needed
  u16* xb  = (u16*)d_ws;                       // 4096*1024  (8 MB)
  u16* Wab = xb  + (size_t)4096 * 1024;        // 3072*1024  (6 MB)
  u16* Wob = Wab + (size_t)3072 * 1024;        // 1024*1024  (2 MB)
  u16* qk  = Wob + (size_t)1024 * 1024;        // 4096*2048  (16 MB) Q|K only
  u16* z   = qk  + (size_t)4096 * 2048;        // 4096*1024  (8 MB)
  u16* vt  = z   + (size_t)4096 * 1024;        // 2048*2048  (8 MB) V transposed

  cvt3_kernel<<<8192, 256, 0, stream>>>(x, Wa, Wo, xb, 1048576, 786432, 262144);

  // fused: Q,K -> qk (width 2048); V -> vt (transposed)
  gemm_bt<2, 128><<<dim3(32, 24), 256, 0, stream>>>(xb, Wab, qk, vt, 4096, 3072, 1024);

  attn_flash4<<<dim3(16, 2 * NH), 256, 0, stream>>>(qk, vt, z);

  gemm_bt<0, 64><<<dim3(32, 16), 256, 0, stream>>>(z, Wob, out, nullptr, 4096, 1024, 1024);
}

// Round 8
// 179.292 us; speedup vs baseline: 1.0906x; 1.0906x over previous
//
#include <hip/hip_runtime.h>
#include <cstddef>

typedef unsigned short u16;
typedef __attribute__((ext_vector_type(4))) float floatx4;
typedef __attribute__((ext_vector_type(8))) short short8;

#define TT 2048
#define DD 1024
#define NH 16
#define ATT_SCALE (1.0f / 32.0f)
#define PSTR 72  // padded LDS row stride (u16)

__device__ __forceinline__ u16 f2bf(float f) {
  unsigned u = __builtin_bit_cast(unsigned, f);
  u += 0x7fffu + ((u >> 16) & 1u);  // RNE
  return (u16)(u >> 16);
}

// pack two f32 -> (bf16,bf16) in one u32, a in low half (RNE)
__device__ __forceinline__ unsigned pack2(float a, float b) {
#if __has_builtin(__builtin_amdgcn_cvt_pk_bf16_f32)
  auto t = __builtin_amdgcn_cvt_pk_bf16_f32(a, b);
  return __builtin_bit_cast(unsigned, t);
#else
  unsigned ua = __builtin_bit_cast(unsigned, a);
  ua += 0x7fffu + ((ua >> 16) & 1u);
  unsigned ub = __builtin_bit_cast(unsigned, b);
  ub += 0x7fffu + ((ub >> 16) & 1u);
  return (ua >> 16) | (ub & 0xffff0000u);
#endif
}

// async global->LDS, 16B per lane (LDS dest wave-uniform base + lane*16)
__device__ __forceinline__ void g2l16(const u16* g, u16* l) {
#if __has_builtin(__builtin_amdgcn_global_load_lds)
  __builtin_amdgcn_global_load_lds(
      (const __attribute__((address_space(1))) unsigned int*)g,
      (__attribute__((address_space(3))) unsigned int*)l, 16, 0, 0);
#else
  *(int4*)l = *(const int4*)g;
#endif
}

// scale bf16x8 by 1/32 (exact: exponent shift)
__device__ __forceinline__ short8 scale_q(short8 q) {
  short8 r;
#pragma unroll
  for (int i = 0; i < 8; ++i) {
    float f = __builtin_bit_cast(float, ((unsigned)(u16)q[i]) << 16) * ATT_SCALE;
    r[i] = (short)f2bf(f);
  }
  return r;
}

// one kernel for all three fp32->bf16 conversions (outputs contiguous in ws)
__global__ __launch_bounds__(256) void cvt3_kernel(const float* __restrict__ a,
                                                   const float* __restrict__ b,
                                                   const float* __restrict__ c,
                                                   u16* __restrict__ out,
                                                   int na, int nb, int nc) {
  int i = blockIdx.x * 256 + threadIdx.x;
  const float* src;
  int j;
  if (i < na) { src = a; j = i; }
  else if (i < na + nb) { src = b; j = i - na; }
  else if (i < na + nb + nc) { src = c; j = i - na - nb; }
  else return;
  float4 v = ((const float4*)src)[j];
  ((ushort4*)out)[i] = make_ushort4(f2bf(v.x), f2bf(v.y), f2bf(v.z), f2bf(v.w));
}

// C[m,n] = sum_k A[m,k]*Bm[n,k]. 128xBN tile, BK=32, global_load_lds staging.
// MODE 0: fp32 out (width N). MODE 1: bf16 out (width N).
// MODE 2 (qkv-fused): cols<2048 -> bf16 qk buffer (width 2048);
//                     cols>=2048 -> V written TRANSPOSED to vt[(b*1024+e-2048)*2048+t].
template <int MODE, int BN>
__global__ __launch_bounds__(256) void gemm_bt(const u16* __restrict__ A,
                                               const u16* __restrict__ Bm,
                                               void* __restrict__ C,
                                               u16* __restrict__ vt,
                                               int M, int N, int K) {
  constexpr int NT = BN / 32;
  __shared__ u16 As[128 * 32];
  __shared__ u16 Bs[BN * 32];
  const int tid = threadIdx.x;
  const int lane = tid & 63;
  const int wave = tid >> 6;
  const int quad = lane >> 4;
  const int l16 = lane & 15;
  const int wm = (wave >> 1) * 64;
  const int wn = (wave & 1) * (BN / 2);
  const int m0 = blockIdx.x * 128;
  const int n0 = blockIdx.y * BN;

  const int srow = wave * 16 + (lane >> 2);
  const int scol = (lane & 3) * 8;
  const int sl = wave * 512 + lane * 8;

  floatx4 acc[4][NT] = {};

  for (int k0 = 0; k0 < K; k0 += 32) {
    __syncthreads();
    g2l16(&A[(size_t)(m0 + srow) * K + k0 + scol], &As[sl]);
    g2l16(&A[(size_t)(m0 + 64 + srow) * K + k0 + scol], &As[2048 + sl]);
    g2l16(&Bm[(size_t)(n0 + srow) * K + k0 + scol], &Bs[sl]);
    if (BN == 128)
      g2l16(&Bm[(size_t)(n0 + 64 + srow) * K + k0 + scol], &Bs[2048 + sl]);
    __syncthreads();

    short8 af[4];
#pragma unroll
    for (int mt = 0; mt < 4; ++mt)
      af[mt] = *(const short8*)&As[(wm + mt * 16 + l16) * 32 + quad * 8];
#pragma unroll
    for (int nt = 0; nt < NT; ++nt) {
      short8 bf = *(const short8*)&Bs[(wn + nt * 16 + l16) * 32 + quad * 8];
#pragma unroll
      for (int mt = 0; mt < 4; ++mt)
        acc[mt][nt] = __builtin_amdgcn_mfma_f32_16x16x32_bf16(af[mt], bf, acc[mt][nt], 0, 0, 0);
    }
  }

  if (MODE == 2 && n0 >= 2048) {
    // V region: transposed store. whole 128-row tile shares one batch (2048%128==0)
    const int bidx = m0 >> 11;
    const int tbase = (m0 & 2047) + wm;
#pragma unroll
    for (int mt = 0; mt < 4; ++mt)
#pragma unroll
      for (int nt = 0; nt < NT; ++nt) {
        int gn = n0 + wn + nt * 16 + l16;
        size_t vrow = (size_t)(bidx * 1024 + gn - 2048);
        int t = tbase + mt * 16 + quad * 4;
        uint2 val;
        val.x = pack2(acc[mt][nt][0], acc[mt][nt][1]);
        val.y = pack2(acc[mt][nt][2], acc[mt][nt][3]);
        *(uint2*)&vt[vrow * TT + t] = val;
      }
  } else {
    const int cw = (MODE == 2) ? 2048 : N;
#pragma unroll
    for (int mt = 0; mt < 4; ++mt)
#pragma unroll
      for (int nt = 0; nt < NT; ++nt)
#pragma unroll
        for (int r = 0; r < 4; ++r) {
          int gm = m0 + wm + mt * 16 + quad * 4 + r;
          int gn = n0 + wn + nt * 16 + l16;
          float v = acc[mt][nt][r];
          if (MODE >= 1)
            ((u16*)C)[(size_t)gm * cw + gn] = f2bf(v);
          else
            ((float*)C)[(size_t)gm * cw + gn] = v;
        }
  }
}

// Paired flash attention, 512 threads = 4 q-slices x 2 key-parities.
// Unnormalized exp is key-associative: parity waves accumulate disjoint
// key-tile partials (kt === par mod 2), combined once at the end via LDS.
// flash3-orientation inner loop (measured best). 55.3 KB LDS -> 2 blocks/CU.
__global__ __launch_bounds__(512) void attn_flash5(const u16* __restrict__ qk,
                                                   const u16* __restrict__ vt,
                                                   u16* __restrict__ z) {
  __shared__ u16 Ks[2][64 * PSTR];   // per key-parity tile: Ks[p][key][d]
  __shared__ u16 Vs[2][64 * PSTR];   // Vs[p][d][key]
  __shared__ u16 Ps[8][16 * PSTR];   // per-wave P round-trip (reused B then A)

  const int tid = threadIdx.x;
  const int lane = tid & 63;
  const int wave = tid >> 6;   // 0..7
  const int qs = wave & 3;     // q-slice (16 rows)
  const int par = wave >> 2;   // key parity
  const int quad = lane >> 4;
  const int l16 = lane & 15;

  const int p = blockIdx.x;  // 0..15
  const int qtA = p, qtB = 31 - p;
  const int bh = blockIdx.y;
  const int b = bh >> 4, h = bh & 15;

  const size_t bbase = (size_t)b * TT * 2048;
  const u16* qg = qk + bbase + h * 64;
  const u16* kg = qk + bbase + 1024 + h * 64;
  const u16* vtg = vt + (size_t)bh * 64 * TT;

  short8 qfA[2], qfB[2];
  {
    const size_t ra = (size_t)(qtA * 64 + qs * 16 + l16) * 2048;
    const size_t rb = (size_t)(qtB * 64 + qs * 16 + l16) * 2048;
    qfA[0] = scale_q(*(const short8*)&qg[ra + quad * 8]);
    qfA[1] = scale_q(*(const short8*)&qg[ra + 32 + quad * 8]);
    qfB[0] = scale_q(*(const short8*)&qg[rb + quad * 8]);
    qfB[1] = scale_q(*(const short8*)&qg[rb + 32 + quad * 8]);
  }

  floatx4 OA[4] = {}, OB[4] = {};
  float psA[4] = {}, psB[4] = {};

  // staging map: threads 0..255 stage tile 2m, 256..511 stage tile 2m+1
  const int tsel = tid >> 8;
  const int t8 = tid & 255;
  const int str = t8 >> 2, sc = (t8 & 3) * 16;

  const int nktB = qtB + 1;
  const int M = (nktB + 1) >> 1;
  const int qrbA = qtA * 64 + qs * 16 + quad * 4;  // +r
  const int qrbB = qtB * 64 + qs * 16 + quad * 4;

  for (int m = 0; m < M; ++m) {
    const int kt = 2 * m + par;    // this wave's key tile
    const int kt0 = kt * 64;
    __syncthreads();  // previous tiles consumed
    {
      const int kst = 2 * m + tsel;
      if (kst < nktB) {
        *(int4*)&Ks[tsel][str * PSTR + sc] =
            *(const int4*)&kg[(size_t)(kst * 64 + str) * 2048 + sc];
        *(int4*)&Ks[tsel][str * PSTR + sc + 8] =
            *(const int4*)&kg[(size_t)(kst * 64 + str) * 2048 + sc + 8];
        *(int4*)&Vs[tsel][str * PSTR + sc] =
            *(const int4*)&vtg[(size_t)str * TT + kst * 64 + sc];
        *(int4*)&Vs[tsel][str * PSTR + sc + 8] =
            *(const int4*)&vtg[(size_t)str * TT + kst * 64 + sc + 8];
      }
    }
    __syncthreads();

    if (kt < nktB) {
      // ---- B tile ----
      floatx4 s[4];
#pragma unroll
      for (int nt = 0; nt < 4; ++nt) {
        short8 k0 = *(const short8*)&Ks[par][(nt * 16 + l16) * PSTR + quad * 8];
        short8 k1 = *(const short8*)&Ks[par][(nt * 16 + l16) * PSTR + 32 + quad * 8];
        floatx4 zz = {0.f, 0.f, 0.f, 0.f};
        s[nt] = __builtin_amdgcn_mfma_f32_16x16x32_bf16(qfB[0], k0, zz, 0, 0, 0);
        s[nt] = __builtin_amdgcn_mfma_f32_16x16x32_bf16(qfB[1], k1, s[nt], 0, 0, 0);
      }
      if (kt == qtB) {
#pragma unroll
        for (int nt = 0; nt < 4; ++nt)
#pragma unroll
          for (int r = 0; r < 4; ++r) {
            int kk = kt0 + nt * 16 + l16;
            float pv = (kk <= qrbB + r) ? __expf(s[nt][r]) : 0.f;
            psB[r] += pv;
            Ps[wave][(quad * 4 + r) * PSTR + nt * 16 + l16] = f2bf(pv);
          }
      } else {
#pragma unroll
        for (int nt = 0; nt < 4; ++nt)
#pragma unroll
          for (int r = 0; r < 4; ++r) {
            float pv = __expf(s[nt][r]);
            psB[r] += pv;
            Ps[wave][(quad * 4 + r) * PSTR + nt * 16 + l16] = f2bf(pv);
          }
      }
      {
        short8 p0 = *(const short8*)&Ps[wave][l16 * PSTR + quad * 8];
        short8 p1 = *(const short8*)&Ps[wave][l16 * PSTR + 32 + quad * 8];
#pragma unroll
        for (int nt = 0; nt < 4; ++nt) {
          short8 v0 = *(const short8*)&Vs[par][(nt * 16 + l16) * PSTR + quad * 8];
          short8 v1 = *(const short8*)&Vs[par][(nt * 16 + l16) * PSTR + 32 + quad * 8];
          OB[nt] = __builtin_amdgcn_mfma_f32_16x16x32_bf16(p0, v0, OB[nt], 0, 0, 0);
          OB[nt] = __builtin_amdgcn_mfma_f32_16x16x32_bf16(p1, v1, OB[nt], 0, 0, 0);
        }
      }

      // ---- A tile (reuses Ps[wave]; in-wave DS ordering makes this safe) ----
      if (kt <= qtA) {
#pragma unroll
        for (int nt = 0; nt < 4; ++nt) {
          short8 k0 = *(const short8*)&Ks[par][(nt * 16 + l16) * PSTR + quad * 8];
          short8 k1 = *(const short8*)&Ks[par][(nt * 16 + l16) * PSTR + 32 + quad * 8];
          floatx4 zz = {0.f, 0.f, 0.f, 0.f};
          s[nt] = __builtin_amdgcn_mfma_f32_16x16x32_bf16(qfA[0], k0, zz, 0, 0, 0);
          s[nt] = __builtin_amdgcn_mfma_f32_16x16x32_bf16(qfA[1], k1, s[nt], 0, 0, 0);
        }
        if (kt == qtA) {
#pragma unroll
          for (int nt = 0; nt < 4; ++nt)
#pragma unroll
            for (int r = 0; r < 4; ++r) {
              int kk = kt0 + nt * 16 + l16;
              float pv = (kk <= qrbA + r) ? __expf(s[nt][r]) : 0.f;
              psA[r] += pv;
              Ps[wave][(quad * 4 + r) * PSTR + nt * 16 + l16] = f2bf(pv);
            }
        } else {
#pragma unroll
          for (int nt = 0; nt < 4; ++nt)
#pragma unroll
            for (int r = 0; r < 4; ++r) {
              float pv = __expf(s[nt][r]);
              psA[r] += pv;
              Ps[wave][(quad * 4 + r) * PSTR + nt * 16 + l16] = f2bf(pv);
            }
        }
        short8 p0 = *(const short8*)&Ps[wave][l16 * PSTR + quad * 8];
        short8 p1 = *(const short8*)&Ps[wave][l16 * PSTR + 32 + quad * 8];
#pragma unroll
        for (int nt = 0; nt < 4; ++nt) {
          short8 v0 = *(const short8*)&Vs[par][(nt * 16 + l16) * PSTR + quad * 8];
          short8 v1 = *(const short8*)&Vs[par][(nt * 16 + l16) * PSTR + 32 + quad * 8];
          OA[nt] = __builtin_amdgcn_mfma_f32_16x16x32_bf16(p0, v0, OA[nt], 0, 0, 0);
          OA[nt] = __builtin_amdgcn_mfma_f32_16x16x32_bf16(p1, v1, OA[nt], 0, 0, 0);
        }
      }
    }
  }

  // row-sum partials over this lane's 16 columns -> full row sums
#pragma unroll
  for (int off = 1; off < 16; off <<= 1)
#pragma unroll
    for (int r = 0; r < 4; ++r) {
      psA[r] += __shfl_xor(psA[r], off, 64);
      psB[r] += __shfl_xor(psB[r], off, 64);
    }

  // cross-parity combine through Ps scratch (two phases: A then B)
  float* red = (float*)Ps;        // 4608 floats available
  float* lred = red + 4096;       // 16 KB offset: 4*16 = 64 floats used
  __syncthreads();
  if (par == 1) {
#pragma unroll
    for (int nt = 0; nt < 4; ++nt)
#pragma unroll
      for (int r = 0; r < 4; ++r)
        red[(qs * 16 + quad * 4 + r) * 64 + nt * 16 + l16] = OA[nt][r];
    if (l16 == 0)
#pragma unroll
      for (int r = 0; r < 4; ++r) lred[qs * 16 + quad * 4 + r] = psA[r];
  }
  __syncthreads();
  if (par == 0) {
#pragma unroll
    for (int r = 0; r < 4; ++r) {
      int row = qs * 16 + quad * 4 + r;
      float rl = 1.0f / (psA[r] + lred[row]);
      int qa = qtA * 64 + row;
#pragma unroll
      for (int nt = 0; nt < 4; ++nt) {
        float o = OA[nt][r] + red[row * 64 + nt * 16 + l16];
        z[(size_t)(b * TT + qa) * DD + h * 64 + nt * 16 + l16] = f2bf(o * rl);
      }
    }
  }
  __syncthreads();
  if (par == 1) {
#pragma unroll
    for (int nt = 0; nt < 4; ++nt)
#pragma unroll
      for (int r = 0; r < 4; ++r)
        red[(qs * 16 + quad * 4 + r) * 64 + nt * 16 + l16] = OB[nt][r];
    if (l16 == 0)
#pragma unroll
      for (int r = 0; r < 4; ++r) lred[qs * 16 + quad * 4 + r] = psB[r];
  }
  __syncthreads();
  if (par == 0) {
#pragma unroll
    for (int r = 0; r < 4; ++r) {
      int row = qs * 16 + quad * 4 + r;
      float rl = 1.0f / (psB[r] + lred[row]);
      int qb = qtB * 64 + row;
#pragma unroll
      for (int nt = 0; nt < 4; ++nt) {
        float o = OB[nt][r] + red[row * 64 + nt * 16 + l16];
        z[(size_t)(b * TT + qb) * DD + h * 64 + nt * 16 + l16] = f2bf(o * rl);
      }
    }
  }
}

extern "C" void kernel_launch(void* const* d_in, const int* in_sizes, int n_in,
                              void* d_out, int out_size, void* d_ws, size_t ws_size,
                              hipStream_t stream) {
  const float* x  = (const float*)d_in[0];   // [2,2048,1024]
  const float* Wa = (const float*)d_in[1];   // [3072,1024]
  const float* Wo = (const float*)d_in[2];   // [1024,1024]
  float* out = (float*)d_out;                // [2,2048,1024] fp32

  // 48 MB workspace
  u16* xb  = (u16*)d_ws;                       // 4096*1024  (8 MB)
  u16* Wab = xb  + (size_t)4096 * 1024;        // 3072*1024  (6 MB)
  u16* Wob = Wab + (size_t)3072 * 1024;        // 1024*1024  (2 MB)
  u16* qk  = Wob + (size_t)1024 * 1024;        // 4096*2048  (16 MB) Q|K only
  u16* z   = qk  + (size_t)4096 * 2048;        // 4096*1024  (8 MB)
  u16* vt  = z   + (size_t)4096 * 1024;        // 2048*2048  (8 MB) V transposed

  cvt3_kernel<<<8192, 256, 0, stream>>>(x, Wa, Wo, xb, 1048576, 786432, 262144);

  // fused: Q,K -> qk (width 2048); V -> vt (transposed)
  gemm_bt<2, 128><<<dim3(32, 24), 256, 0, stream>>>(xb, Wab, qk, vt, 4096, 3072, 1024);

  attn_flash5<<<dim3(16, 2 * NH), 512, 0, stream>>>(qk, vt, z);

  gemm_bt<0, 64><<<dim3(32, 16), 256, 0, stream>>>(z, Wob, out, nullptr, 4096, 1024, 1024);
}